// Round 11
// baseline (627.016 us; speedup 1.0000x reference)
//
#include <hip/hip_runtime.h>

#define NFEAT 128

// ---------------- LDS-privatized degree histogram (no global atomics) ----------------
// u8-packed counts: 65536 nodes/chunk as 4 x u8 per u32 -> 64 KB LDS, npass=2.
// Grid (HBLOCKS, npass, 2): z=0 histograms src into pA, z=1 dst into pB.
constexpr int HCHUNK = 65536;
constexpr int HBLOCKS = 128;

__global__ __launch_bounds__(256) void hist3_k(const int* __restrict__ src,
                                               const int* __restrict__ dst, int ne, int n,
                                               unsigned int* __restrict__ pA,
                                               unsigned int* __restrict__ pB) {
    __shared__ unsigned int cnt[HCHUNK / 4];
    const int* __restrict__ idx = blockIdx.z ? dst : src;
    unsigned int* __restrict__ partials = blockIdx.z ? pB : pA;
    int b = blockIdx.x;
    int p = blockIdx.y;
    int per = (ne + HBLOCKS - 1) / HBLOCKS;
    int e0 = b * per, e1 = min(e0 + per, ne);
    int base = p * HCHUNK;
    for (int i = threadIdx.x; i < HCHUNK / 4; i += 256) cnt[i] = 0;
    __syncthreads();
    for (int e = e0 + threadIdx.x; e < e1; e += 256) {
        int d = idx[e] - base;
        if ((unsigned)d < (unsigned)HCHUNK) {
            atomicAdd(&cnt[d >> 2], 1u << ((d & 3) * 8));
        }
    }
    __syncthreads();
    unsigned int* dstp = partials + ((size_t)p * HBLOCKS + b) * (HCHUNK / 4);
    for (int i = threadIdx.x; i < HCHUNK / 4; i += 256) dstp[i] = cnt[i];
}

// y=0: sum pA -> ns (norm only). y=1: sum+exclusive-prefix pB -> deg, ndv.
__global__ void sum_prefix2_k(unsigned int* __restrict__ pA, unsigned int* __restrict__ pB,
                              int* __restrict__ deg, float* __restrict__ ns,
                              float* __restrict__ ndv, int n, int npass) {
    int slot = blockIdx.x * 256 + threadIdx.x;
    int total = npass * (HCHUNK / 4);
    if (slot >= total) return;
    bool pfx = (blockIdx.y != 0);
    unsigned int* partials = pfx ? pB : pA;
    float* nrm = pfx ? ndv : ns;
    int p = slot / (HCHUNK / 4);
    int j4 = slot - p * (HCHUNK / 4);
    unsigned int* base = partials + (size_t)p * HBLOCKS * (HCHUNK / 4) + j4;
    unsigned c0 = 0, c1 = 0, c2 = 0, c3 = 0;
    for (int b = 0; b < HBLOCKS; b++) {
        unsigned v = base[(size_t)b * (HCHUNK / 4)];
        if (pfx) base[(size_t)b * (HCHUNK / 4)] = c0 | (c1 << 8) | (c2 << 16) | (c3 << 24);
        c0 += v & 0xffu;
        c1 += (v >> 8) & 0xffu;
        c2 += (v >> 16) & 0xffu;
        c3 += (v >> 24) & 0xffu;
    }
    int node = p * HCHUNK + 4 * j4;
    unsigned c[4] = {c0, c1, c2, c3};
#pragma unroll
    for (int q = 0; q < 4; q++) {
        if (node + q < n) {
            if (pfx) deg[node + q] = (int)c[q];
            nrm[node + q] = rsqrtf(fmaxf((float)c[q], 1.f));
        }
    }
}

// ---------------- exclusive scan of deg_in -> row_ptr ----------------
__global__ void scan1_k(const int* __restrict__ deg, int* __restrict__ rp,
                        int* __restrict__ partials, int n) {
    __shared__ int tmp[256];
    int t = threadIdx.x;
    int i = blockIdx.x * 256 + t;
    int v = (i < n) ? deg[i] : 0;
    tmp[t] = v;
    __syncthreads();
    int val = v;
    for (int off = 1; off < 256; off <<= 1) {
        int add = (t >= off) ? tmp[t - off] : 0;
        __syncthreads();
        val += add;
        tmp[t] = val;
        __syncthreads();
    }
    if (i < n) rp[i] = val - v;
    if (t == 255) partials[blockIdx.x] = val;
}

__global__ void scan2_k(int* __restrict__ partials, int nb) {
    __shared__ int tmp[512];
    int t = threadIdx.x;
    int v = (t < nb) ? partials[t] : 0;
    tmp[t] = v;
    __syncthreads();
    int val = v;
    for (int off = 1; off < 512; off <<= 1) {
        int add = (t >= off) ? tmp[t - off] : 0;
        __syncthreads();
        val += add;
        tmp[t] = val;
        __syncthreads();
    }
    if (t < nb) partials[t] = val - v;
}

__global__ void scan3_k(int* __restrict__ rp, const int* __restrict__ partials,
                        const int* __restrict__ deg, int n) {
    int i = blockIdx.x * 256 + threadIdx.x;
    if (i < n) {
        int r = rp[i] + partials[blockIdx.x];
        rp[i] = r;
        if (i == n - 1) rp[n] = r + deg[i];
    }
}

// ---------------- atomic-free CSR fill (counting-sort scatter, pass-parallel) -------
__global__ __launch_bounds__(256) void fill2_k(const int* __restrict__ src,
                                               const int* __restrict__ dst,
                                               const int* __restrict__ rp,
                                               const unsigned int* __restrict__ prefix,
                                               int* __restrict__ esrc, int ne, int n) {
    __shared__ unsigned int cnt[HCHUNK / 4];
    int b = blockIdx.x;
    int p = blockIdx.y;
    int per = (ne + HBLOCKS - 1) / HBLOCKS;
    int e0 = b * per, e1 = min(e0 + per, ne);
    int base = p * HCHUNK;
    for (int i = threadIdx.x; i < HCHUNK / 4; i += 256) cnt[i] = 0;
    __syncthreads();
    const unsigned int* pf = prefix + ((size_t)p * HBLOCKS + b) * (HCHUNK / 4);
    for (int e = e0 + threadIdx.x; e < e1; e += 256) {
        int d = dst[e] - base;
        if ((unsigned)d < (unsigned)HCHUNK) {
            int sh = (d & 3) * 8;
            unsigned old = atomicAdd(&cnt[d >> 2], 1u << sh);  // LDS atomic only
            int rank = (int)((old >> sh) & 0xffu);
            int pos = rp[base + d] + (int)((pf[d >> 2] >> sh) & 0xffu) + rank;
            esrc[pos] = src[e];
        }
    }
}

// ---------------- GEMM v3 (NCOL=128): 8x8 acc/thread, BM=128, BK=16 ----------------
// 64 FMA per 4 ds_read_b128 (0.5 B/FLOP); LDS 16.6 KB -> multiple blocks/CU.
template <bool HAS_V>
__global__ __launch_bounds__(256) void gemm3_k(
    const float* __restrict__ X, const float* __restrict__ W,
    const float* __restrict__ rs, const float* __restrict__ vvec,
    float* __restrict__ H, int n) {
    constexpr int BK = 16;
    constexpr int BM = 128;
    __shared__ float Xs[BK][BM + 4];
    __shared__ float Ws[BK][128];
    int tid = threadIdx.x;
    int tx = tid & 15;   // 16 col groups x 8 cols
    int ty = tid >> 4;   // 16 row groups x 8 rows
    int row0 = blockIdx.x * BM;
    float acc[8][8] = {};
    for (int k0 = 0; k0 < NFEAT; k0 += BK) {
        // stage W tile: BK x 128 as float4 (512 stores / 256 threads)
        for (int idx = tid; idx < BK * 32; idx += 256) {
            int k = idx >> 5, cq = idx & 31;
            *(float4*)&Ws[k][cq * 4] = *(const float4*)&W[(size_t)(k0 + k) * 128 + cq * 4];
        }
        // stage X tile transposed: BM rows x BK k (512 float4 loads)
        for (int idx = tid; idx < BM * (BK / 4); idx += 256) {
            int m = idx >> 2, kq = idx & 3;
            int gm = row0 + m;
            float4 v = {0.f, 0.f, 0.f, 0.f};
            float sc = 0.f;
            if (gm < n) {
                v = *(const float4*)&X[(size_t)gm * NFEAT + k0 + kq * 4];
                sc = rs[gm];
            }
            Xs[kq * 4 + 0][m] = v.x * sc;
            Xs[kq * 4 + 1][m] = v.y * sc;
            Xs[kq * 4 + 2][m] = v.z * sc;
            Xs[kq * 4 + 3][m] = v.w * sc;
        }
        __syncthreads();
#pragma unroll
        for (int k = 0; k < BK; k++) {
            float4 b0 = *(const float4*)&Ws[k][tx * 8];
            float4 b1 = *(const float4*)&Ws[k][tx * 8 + 4];
            float4 a0 = *(const float4*)&Xs[k][ty * 8];
            float4 a1 = *(const float4*)&Xs[k][ty * 8 + 4];
            float av[8] = {a0.x, a0.y, a0.z, a0.w, a1.x, a1.y, a1.z, a1.w};
            float bv[8] = {b0.x, b0.y, b0.z, b0.w, b1.x, b1.y, b1.z, b1.w};
#pragma unroll
            for (int i = 0; i < 8; i++)
#pragma unroll
                for (int j = 0; j < 8; j++) acc[i][j] += av[i] * bv[j];
        }
        __syncthreads();
    }
#pragma unroll
    for (int i = 0; i < 8; i++) {
        int gm = row0 + ty * 8 + i;
        if (gm < n) {
            float4 o0, o1;
            o0.x = acc[i][0]; o0.y = acc[i][1]; o0.z = acc[i][2]; o0.w = acc[i][3];
            o1.x = acc[i][4]; o1.y = acc[i][5]; o1.z = acc[i][6]; o1.w = acc[i][7];
            if (HAS_V) {
                float sc = rs[gm];
                o0.x += sc * vvec[tx * 8 + 0];
                o0.y += sc * vvec[tx * 8 + 1];
                o0.z += sc * vvec[tx * 8 + 2];
                o0.w += sc * vvec[tx * 8 + 3];
                o1.x += sc * vvec[tx * 8 + 4];
                o1.y += sc * vvec[tx * 8 + 5];
                o1.z += sc * vvec[tx * 8 + 6];
                o1.w += sc * vvec[tx * 8 + 7];
            }
            *(float4*)&H[(size_t)gm * 128 + tx * 8] = o0;
            *(float4*)&H[(size_t)gm * 128 + tx * 8 + 4] = o1;
        }
    }
}

// ---------------- GEMM v2 (NCOL=64): 8x4 acc/thread, BM=128 ------------------------
template <int NCOL, bool HAS_V>
__global__ __launch_bounds__(256) void gemm2_k(
    const float* __restrict__ X, const float* __restrict__ W,
    const float* __restrict__ rs, const float* __restrict__ vvec,
    float* __restrict__ H, int n) {
    constexpr int BK = 32;
    constexpr int CG = NCOL / 4;
    constexpr int RG = 256 / CG;
    constexpr int BM = RG * 8;
    __shared__ float Xs[BK][BM + 4];
    __shared__ float Ws[BK][NCOL];
    int tid = threadIdx.x;
    int tx = tid % CG;
    int ty = tid / CG;
    int row0 = blockIdx.x * BM;
    float acc[8][4] = {};
    for (int k0 = 0; k0 < NFEAT; k0 += BK) {
        for (int idx = tid; idx < BK * NCOL / 4; idx += 256) {
            int k = idx / (NCOL / 4);
            int cq = idx % (NCOL / 4);
            *(float4*)&Ws[k][cq * 4] = *(const float4*)&W[(size_t)(k0 + k) * NCOL + cq * 4];
        }
        for (int idx = tid; idx < BM * (BK / 4); idx += 256) {
            int m = idx / (BK / 4);
            int kq = idx % (BK / 4);
            int gm = row0 + m;
            float4 v = {0.f, 0.f, 0.f, 0.f};
            float sc = 0.f;
            if (gm < n) {
                v = *(const float4*)&X[(size_t)gm * NFEAT + k0 + kq * 4];
                sc = rs[gm];
            }
            Xs[kq * 4 + 0][m] = v.x * sc;
            Xs[kq * 4 + 1][m] = v.y * sc;
            Xs[kq * 4 + 2][m] = v.z * sc;
            Xs[kq * 4 + 3][m] = v.w * sc;
        }
        __syncthreads();
#pragma unroll
        for (int k = 0; k < BK; k++) {
            float4 b = *(const float4*)&Ws[k][tx * 4];
            float4 a0 = *(const float4*)&Xs[k][ty * 8];
            float4 a1 = *(const float4*)&Xs[k][ty * 8 + 4];
            float av[8] = {a0.x, a0.y, a0.z, a0.w, a1.x, a1.y, a1.z, a1.w};
            float bv[4] = {b.x, b.y, b.z, b.w};
#pragma unroll
            for (int i = 0; i < 8; i++)
#pragma unroll
                for (int j = 0; j < 4; j++) acc[i][j] += av[i] * bv[j];
        }
        __syncthreads();
    }
#pragma unroll
    for (int i = 0; i < 8; i++) {
        int gm = row0 + ty * 8 + i;
        if (gm < n) {
            float4 o;
            o.x = acc[i][0]; o.y = acc[i][1]; o.z = acc[i][2]; o.w = acc[i][3];
            if (HAS_V) {
                float sc = rs[gm];
                o.x += sc * vvec[tx * 4 + 0];
                o.y += sc * vvec[tx * 4 + 1];
                o.z += sc * vvec[tx * 4 + 2];
                o.w += sc * vvec[tx * 4 + 3];
            }
            *(float4*)&H[(size_t)gm * NCOL + tx * 4] = o;
        }
    }
}

// ---------------- CSR aggregation: one 64-lane wave per node, float2/lane ----------
template <int F, bool RELU>
__global__ __launch_bounds__(256) void agg3_k(const float* __restrict__ H,
                                              const int* __restrict__ rp,
                                              const int* __restrict__ esrc,
                                              const float* __restrict__ nd,
                                              const float* __restrict__ bias,
                                              float* __restrict__ out, int n) {
    constexpr int VW = F / 64;  // 2 (F=128) or 1 (F=64)
    int node = blockIdx.x * 4 + (threadIdx.x >> 6);
    if (node >= n) return;
    int lane = threadIdx.x & 63;
    int e0 = rp[node], e1 = rp[node + 1];
    float ax = 0.f, ay = 0.f;
    int e = e0;
    for (; e + 8 <= e1; e += 8) {
        int s[8];
#pragma unroll
        for (int j = 0; j < 8; j++) s[j] = esrc[e + j];
#pragma unroll
        for (int j = 0; j < 8; j++) {
            if (VW == 2) {
                float2 v = *(const float2*)(H + (size_t)s[j] * F + lane * 2);
                ax += v.x;
                ay += v.y;
            } else {
                ax += H[(size_t)s[j] * F + lane];
            }
        }
    }
    for (; e < e1; e++) {
        int s = esrc[e];
        if (VW == 2) {
            float2 v = *(const float2*)(H + (size_t)s * F + lane * 2);
            ax += v.x;
            ay += v.y;
        } else {
            ax += H[(size_t)s * F + lane];
        }
    }
    float sc = nd[node];
    if (VW == 2) {
        float2 o;
        o.x = ax * sc + bias[lane * 2];
        o.y = ay * sc + bias[lane * 2 + 1];
        if (RELU) {
            o.x = fmaxf(o.x, 0.f);
            o.y = fmaxf(o.y, 0.f);
        }
        *(float2*)(out + (size_t)node * F + lane * 2) = o;
    } else {
        float o = ax * sc + bias[lane];
        if (RELU) o = fmaxf(o, 0.f);
        out[(size_t)node * F + lane] = o;
    }
}

// ---------------- BN stats (two-stage, atomic-free) ----------------
constexpr int CSB = 1024;

__global__ __launch_bounds__(256) void colstats1_k(const float* __restrict__ X,
                                                   float* __restrict__ psum,
                                                   float* __restrict__ psq, int n) {
    __shared__ float sh[256];
    int t = threadIdx.x;
    int c = t & 127;
    int half = t >> 7;
    int rows_per = (n + CSB - 1) / CSB;
    int r0 = blockIdx.x * rows_per;
    int r1 = min(r0 + rows_per, n);
    float s = 0.f, sq = 0.f;
    for (int r = r0 + half; r < r1; r += 2) {
        float v = X[(size_t)r * 128 + c];
        s += v;
        sq += v * v;
    }
    sh[t] = s;
    __syncthreads();
    if (half == 0) psum[(size_t)c * CSB + blockIdx.x] = s + sh[t + 128];
    __syncthreads();
    sh[t] = sq;
    __syncthreads();
    if (half == 0) psq[(size_t)c * CSB + blockIdx.x] = sq + sh[t + 128];
}

__global__ __launch_bounds__(256) void colstats2_k(const float* __restrict__ psum,
                                                   const float* __restrict__ psq,
                                                   float* __restrict__ colsum,
                                                   float* __restrict__ colsq) {
    __shared__ float sh[256];
    int c = blockIdx.x;
    int t = threadIdx.x;
    float s = 0.f, sq = 0.f;
#pragma unroll
    for (int i = 0; i < CSB / 256; i++) {
        s += psum[(size_t)c * CSB + i * 256 + t];
        sq += psq[(size_t)c * CSB + i * 256 + t];
    }
    sh[t] = s;
    __syncthreads();
    for (int off = 128; off > 0; off >>= 1) {
        if (t < off) sh[t] += sh[t + off];
        __syncthreads();
    }
    if (t == 0) colsum[c] = sh[0];
    __syncthreads();
    sh[t] = sq;
    __syncthreads();
    for (int off = 128; off > 0; off >>= 1) {
        if (t < off) sh[t] += sh[t + off];
        __syncthreads();
    }
    if (t == 0) colsq[c] = sh[0];
}

__global__ void bn_prep_k(const float* __restrict__ colsum, const float* __restrict__ colsq,
                          const float* __restrict__ gamma, const float* __restrict__ beta,
                          const float* __restrict__ W2, float* __restrict__ W2p,
                          float* __restrict__ v2, float n) {
    __shared__ float s_s[128], s_t[128];
    int c = threadIdx.x;
    float mu = colsum[c] / n;
    float var = colsq[c] / n - mu * mu;
    float s = gamma[c] * rsqrtf(var + 1e-5f);
    float t = beta[c] - mu * s;
    s_s[c] = s;
    s_t[c] = t;
    __syncthreads();
    float acc = 0.f;
    for (int k = 0; k < 128; k++) {
        float w = W2[k * 128 + c];
        W2p[k * 128 + c] = s_s[k] * w;
        acc += s_t[k] * w;
    }
    v2[c] = acc;
}

extern "C" void kernel_launch(void* const* d_in, const int* in_sizes, int n_in,
                              void* d_out, int out_size, void* d_ws, size_t ws_size,
                              hipStream_t stream) {
    const float* feat = (const float*)d_in[0];
    const int* src = (const int*)d_in[1];
    const int* dst = (const int*)d_in[2];
    const float* W1 = (const float*)d_in[3];
    const float* b1 = (const float*)d_in[4];
    const float* gamma1 = (const float*)d_in[5];
    const float* beta1 = (const float*)d_in[6];
    const float* W2 = (const float*)d_in[7];
    const float* b2 = (const float*)d_in[8];
    const float* W3 = (const float*)d_in[9];
    const float* b3 = (const float*)d_in[10];
    float* out = (float*)d_out;

    int n = in_sizes[0] / NFEAT;
    int ne = in_sizes[1];
    int npass = (n + HCHUNK - 1) / HCHUNK;

    char* ws = (char*)d_ws;
    size_t off = 0;
    auto carve = [&](size_t bytes) -> void* {
        void* p = ws + off;
        off += (bytes + 255) & ~(size_t)255;
        return p;
    };
    float* h    = (float*)carve((size_t)n * NFEAT * 4);
    float* x    = (float*)carve((size_t)n * NFEAT * 4);
    int* esrc   = (int*)carve((size_t)ne * 4);
    int* din_   = (int*)carve((size_t)n * 4);
    float* ns   = (float*)carve((size_t)n * 4);
    float* ndv  = (float*)carve((size_t)n * 4);
    int* rp     = (int*)carve((size_t)(n + 1) * 4);
    int* parts  = (int*)carve(512 * 4);
    float* psum = (float*)carve((size_t)128 * CSB * 4);
    float* psq  = (float*)carve((size_t)128 * CSB * 4);
    float* colsum = (float*)carve(128 * 4);
    float* colsq  = (float*)carve(128 * 4);
    float* W2p  = (float*)carve(128 * 128 * 4);
    float* v2   = (float*)carve(128 * 4);

    // histogram partials alias h: each npass*HBLOCKS*HCHUNK/4 u32 = 16.8 MB; both
    // fit in h (51.2 MB); h first written by gemm1 (after CSR build).
    size_t hpart_elems = (size_t)npass * HBLOCKS * (HCHUNK / 4);
    unsigned int* hpartA = (unsigned int*)h;
    unsigned int* hpartB = hpartA + hpart_elems;

    int nbl = (n + 255) / 256;
    int sbl = (npass * (HCHUNK / 4) + 255) / 256;

    hist3_k<<<dim3(HBLOCKS, npass, 2), 256, 0, stream>>>(src, dst, ne, n, hpartA, hpartB);
    sum_prefix2_k<<<dim3(sbl, 2), 256, 0, stream>>>(hpartA, hpartB, din_, ns, ndv, n, npass);

    scan1_k<<<nbl, 256, 0, stream>>>(din_, rp, parts, n);
    scan2_k<<<1, 512, 0, stream>>>(parts, nbl);
    scan3_k<<<nbl, 256, 0, stream>>>(rp, parts, din_, n);
    fill2_k<<<dim3(HBLOCKS, npass), 256, 0, stream>>>(src, dst, rp, hpartB, esrc, ne, n);

    int agrid = (n + 3) / 4;

    // layer 1: relu(conv(features, W1, b1))
    gemm3_k<false><<<(n + 127) / 128, 256, 0, stream>>>(feat, W1, ns, nullptr, h, n);
    agg3_k<128, true><<<agrid, 256, 0, stream>>>(h, rp, esrc, ndv, b1, x, n);

    // batchnorm folded into W2
    colstats1_k<<<CSB, 256, 0, stream>>>(x, psum, psq, n);
    colstats2_k<<<128, 256, 0, stream>>>(psum, psq, colsum, colsq);
    bn_prep_k<<<1, 128, 0, stream>>>(colsum, colsq, gamma1, beta1, W2, W2p, v2, (float)n);

    // layer 2: relu(conv(BN(x), W2, b2))
    gemm3_k<true><<<(n + 127) / 128, 256, 0, stream>>>(x, W2p, ns, v2, h, n);
    agg3_k<128, true><<<agrid, 256, 0, stream>>>(h, rp, esrc, ndv, b2, x, n);

    // layer 3: conv(x, W3, b3) -> out  (BM=128 for NCOL=64 -> grid (n+127)/128)
    gemm2_k<64, false><<<(n + 127) / 128, 256, 0, stream>>>(x, W3, ns, nullptr, h, n);
    agg3_k<64, false><<<agrid, 256, 0, stream>>>(h, rp, esrc, ndv, b3, out, n);
}

// Round 12
// 567.997 us; speedup vs baseline: 1.1039x; 1.1039x over previous
//
#include <hip/hip_runtime.h>

#define NFEAT 128

// ---------------- LDS-privatized degree histogram (no global atomics) ----------------
// u8-packed counts: 65536 nodes/chunk as 4 x u8 per u32 -> 64 KB LDS, npass=2.
// Grid (HBLOCKS, npass, 2): z=0 histograms src into pA, z=1 dst into pB.
constexpr int HCHUNK = 65536;
constexpr int HBLOCKS = 128;

__global__ __launch_bounds__(256) void hist3_k(const int* __restrict__ src,
                                               const int* __restrict__ dst, int ne, int n,
                                               unsigned int* __restrict__ pA,
                                               unsigned int* __restrict__ pB) {
    __shared__ unsigned int cnt[HCHUNK / 4];
    const int* __restrict__ idx = blockIdx.z ? dst : src;
    unsigned int* __restrict__ partials = blockIdx.z ? pB : pA;
    int b = blockIdx.x;
    int p = blockIdx.y;
    int per = (ne + HBLOCKS - 1) / HBLOCKS;
    int e0 = b * per, e1 = min(e0 + per, ne);
    int base = p * HCHUNK;
    for (int i = threadIdx.x; i < HCHUNK / 4; i += 256) cnt[i] = 0;
    __syncthreads();
    for (int e = e0 + threadIdx.x; e < e1; e += 256) {
        int d = idx[e] - base;
        if ((unsigned)d < (unsigned)HCHUNK) {
            atomicAdd(&cnt[d >> 2], 1u << ((d & 3) * 8));
        }
    }
    __syncthreads();
    unsigned int* dstp = partials + ((size_t)p * HBLOCKS + b) * (HCHUNK / 4);
    for (int i = threadIdx.x; i < HCHUNK / 4; i += 256) dstp[i] = cnt[i];
}

// y=0: sum pA -> ns (norm only). y=1: sum+exclusive-prefix pB -> deg, ndv.
__global__ void sum_prefix2_k(unsigned int* __restrict__ pA, unsigned int* __restrict__ pB,
                              int* __restrict__ deg, float* __restrict__ ns,
                              float* __restrict__ ndv, int n, int npass) {
    int slot = blockIdx.x * 256 + threadIdx.x;
    int total = npass * (HCHUNK / 4);
    if (slot >= total) return;
    bool pfx = (blockIdx.y != 0);
    unsigned int* partials = pfx ? pB : pA;
    float* nrm = pfx ? ndv : ns;
    int p = slot / (HCHUNK / 4);
    int j4 = slot - p * (HCHUNK / 4);
    unsigned int* base = partials + (size_t)p * HBLOCKS * (HCHUNK / 4) + j4;
    unsigned c0 = 0, c1 = 0, c2 = 0, c3 = 0;
    for (int b = 0; b < HBLOCKS; b++) {
        unsigned v = base[(size_t)b * (HCHUNK / 4)];
        if (pfx) base[(size_t)b * (HCHUNK / 4)] = c0 | (c1 << 8) | (c2 << 16) | (c3 << 24);
        c0 += v & 0xffu;
        c1 += (v >> 8) & 0xffu;
        c2 += (v >> 16) & 0xffu;
        c3 += (v >> 24) & 0xffu;
    }
    int node = p * HCHUNK + 4 * j4;
    unsigned c[4] = {c0, c1, c2, c3};
#pragma unroll
    for (int q = 0; q < 4; q++) {
        if (node + q < n) {
            if (pfx) deg[node + q] = (int)c[q];
            nrm[node + q] = rsqrtf(fmaxf((float)c[q], 1.f));
        }
    }
}

// ---------------- exclusive scan of deg_in -> row_ptr ----------------
__global__ void scan1_k(const int* __restrict__ deg, int* __restrict__ rp,
                        int* __restrict__ partials, int n) {
    __shared__ int tmp[256];
    int t = threadIdx.x;
    int i = blockIdx.x * 256 + t;
    int v = (i < n) ? deg[i] : 0;
    tmp[t] = v;
    __syncthreads();
    int val = v;
    for (int off = 1; off < 256; off <<= 1) {
        int add = (t >= off) ? tmp[t - off] : 0;
        __syncthreads();
        val += add;
        tmp[t] = val;
        __syncthreads();
    }
    if (i < n) rp[i] = val - v;
    if (t == 255) partials[blockIdx.x] = val;
}

__global__ void scan2_k(int* __restrict__ partials, int nb) {
    __shared__ int tmp[512];
    int t = threadIdx.x;
    int v = (t < nb) ? partials[t] : 0;
    tmp[t] = v;
    __syncthreads();
    int val = v;
    for (int off = 1; off < 512; off <<= 1) {
        int add = (t >= off) ? tmp[t - off] : 0;
        __syncthreads();
        val += add;
        tmp[t] = val;
        __syncthreads();
    }
    if (t < nb) partials[t] = val - v;
}

__global__ void scan3_k(int* __restrict__ rp, const int* __restrict__ partials,
                        const int* __restrict__ deg, int n) {
    int i = blockIdx.x * 256 + threadIdx.x;
    if (i < n) {
        int r = rp[i] + partials[blockIdx.x];
        rp[i] = r;
        if (i == n - 1) rp[n] = r + deg[i];
    }
}

// ---------------- atomic-free CSR fill (counting-sort scatter, pass-parallel) -------
__global__ __launch_bounds__(256) void fill2_k(const int* __restrict__ src,
                                               const int* __restrict__ dst,
                                               const int* __restrict__ rp,
                                               const unsigned int* __restrict__ prefix,
                                               int* __restrict__ esrc, int ne, int n) {
    __shared__ unsigned int cnt[HCHUNK / 4];
    int b = blockIdx.x;
    int p = blockIdx.y;
    int per = (ne + HBLOCKS - 1) / HBLOCKS;
    int e0 = b * per, e1 = min(e0 + per, ne);
    int base = p * HCHUNK;
    for (int i = threadIdx.x; i < HCHUNK / 4; i += 256) cnt[i] = 0;
    __syncthreads();
    const unsigned int* pf = prefix + ((size_t)p * HBLOCKS + b) * (HCHUNK / 4);
    for (int e = e0 + threadIdx.x; e < e1; e += 256) {
        int d = dst[e] - base;
        if ((unsigned)d < (unsigned)HCHUNK) {
            int sh = (d & 3) * 8;
            unsigned old = atomicAdd(&cnt[d >> 2], 1u << sh);  // LDS atomic only
            int rank = (int)((old >> sh) & 0xffu);
            int pos = rp[base + d] + (int)((pf[d >> 2] >> sh) & 0xffu) + rank;
            esrc[pos] = src[e];
        }
    }
}

// ---------------- GEMM v2: 8x4 acc/thread, BM = RG*8 rows/block (measured-good) ----
template <int NCOL, bool HAS_V>
__global__ __launch_bounds__(256) void gemm2_k(
    const float* __restrict__ X, const float* __restrict__ W,
    const float* __restrict__ rs, const float* __restrict__ vvec,
    float* __restrict__ H, int n) {
    constexpr int BK = 32;
    constexpr int CG = NCOL / 4;     // 32 (NCOL=128) or 16 (NCOL=64)
    constexpr int RG = 256 / CG;     // 8 or 16
    constexpr int BM = RG * 8;       // 64 or 128
    __shared__ float Xs[BK][BM + 4];
    __shared__ float Ws[BK][NCOL];
    int tid = threadIdx.x;
    int tx = tid % CG;
    int ty = tid / CG;
    int row0 = blockIdx.x * BM;
    float acc[8][4] = {};
    for (int k0 = 0; k0 < NFEAT; k0 += BK) {
        for (int idx = tid; idx < BK * NCOL / 4; idx += 256) {
            int k = idx / (NCOL / 4);
            int cq = idx % (NCOL / 4);
            *(float4*)&Ws[k][cq * 4] = *(const float4*)&W[(size_t)(k0 + k) * NCOL + cq * 4];
        }
        for (int idx = tid; idx < BM * (BK / 4); idx += 256) {
            int m = idx / (BK / 4);
            int kq = idx % (BK / 4);
            int gm = row0 + m;
            float4 v = {0.f, 0.f, 0.f, 0.f};
            float sc = 0.f;
            if (gm < n) {
                v = *(const float4*)&X[(size_t)gm * NFEAT + k0 + kq * 4];
                sc = rs[gm];
            }
            Xs[kq * 4 + 0][m] = v.x * sc;
            Xs[kq * 4 + 1][m] = v.y * sc;
            Xs[kq * 4 + 2][m] = v.z * sc;
            Xs[kq * 4 + 3][m] = v.w * sc;
        }
        __syncthreads();
#pragma unroll
        for (int k = 0; k < BK; k++) {
            float4 b = *(const float4*)&Ws[k][tx * 4];
            float4 a0 = *(const float4*)&Xs[k][ty * 8];
            float4 a1 = *(const float4*)&Xs[k][ty * 8 + 4];
            float av[8] = {a0.x, a0.y, a0.z, a0.w, a1.x, a1.y, a1.z, a1.w};
            float bv[4] = {b.x, b.y, b.z, b.w};
#pragma unroll
            for (int i = 0; i < 8; i++)
#pragma unroll
                for (int j = 0; j < 4; j++) acc[i][j] += av[i] * bv[j];
        }
        __syncthreads();
    }
#pragma unroll
    for (int i = 0; i < 8; i++) {
        int gm = row0 + ty * 8 + i;
        if (gm < n) {
            float4 o;
            o.x = acc[i][0]; o.y = acc[i][1]; o.z = acc[i][2]; o.w = acc[i][3];
            if (HAS_V) {
                float sc = rs[gm];
                o.x += sc * vvec[tx * 4 + 0];
                o.y += sc * vvec[tx * 4 + 1];
                o.z += sc * vvec[tx * 4 + 2];
                o.w += sc * vvec[tx * 4 + 3];
            }
            *(float4*)&H[(size_t)gm * NCOL + tx * 4] = o;
        }
    }
}

// ---------------- CSR aggregation: one 64-lane wave per node, float2/lane ----------
template <int F, bool RELU>
__global__ __launch_bounds__(256) void agg3_k(const float* __restrict__ H,
                                              const int* __restrict__ rp,
                                              const int* __restrict__ esrc,
                                              const float* __restrict__ nd,
                                              const float* __restrict__ bias,
                                              float* __restrict__ out, int n) {
    constexpr int VW = F / 64;  // 2 (F=128) or 1 (F=64)
    int node = blockIdx.x * 4 + (threadIdx.x >> 6);
    if (node >= n) return;
    int lane = threadIdx.x & 63;
    int e0 = rp[node], e1 = rp[node + 1];
    float ax = 0.f, ay = 0.f;
    int e = e0;
    for (; e + 8 <= e1; e += 8) {
        int s[8];
#pragma unroll
        for (int j = 0; j < 8; j++) s[j] = esrc[e + j];
#pragma unroll
        for (int j = 0; j < 8; j++) {
            if (VW == 2) {
                float2 v = *(const float2*)(H + (size_t)s[j] * F + lane * 2);
                ax += v.x;
                ay += v.y;
            } else {
                ax += H[(size_t)s[j] * F + lane];
            }
        }
    }
    for (; e < e1; e++) {
        int s = esrc[e];
        if (VW == 2) {
            float2 v = *(const float2*)(H + (size_t)s * F + lane * 2);
            ax += v.x;
            ay += v.y;
        } else {
            ax += H[(size_t)s * F + lane];
        }
    }
    float sc = nd[node];
    if (VW == 2) {
        float2 o;
        o.x = ax * sc + bias[lane * 2];
        o.y = ay * sc + bias[lane * 2 + 1];
        if (RELU) {
            o.x = fmaxf(o.x, 0.f);
            o.y = fmaxf(o.y, 0.f);
        }
        *(float2*)(out + (size_t)node * F + lane * 2) = o;
    } else {
        float o = ax * sc + bias[lane];
        if (RELU) o = fmaxf(o, 0.f);
        out[(size_t)node * F + lane] = o;
    }
}

// ---------------- BN stats (two-stage, atomic-free) ----------------
constexpr int CSB = 1024;

__global__ __launch_bounds__(256) void colstats1_k(const float* __restrict__ X,
                                                   float* __restrict__ psum,
                                                   float* __restrict__ psq, int n) {
    __shared__ float sh[256];
    int t = threadIdx.x;
    int c = t & 127;
    int half = t >> 7;
    int rows_per = (n + CSB - 1) / CSB;
    int r0 = blockIdx.x * rows_per;
    int r1 = min(r0 + rows_per, n);
    float s = 0.f, sq = 0.f;
    for (int r = r0 + half; r < r1; r += 2) {
        float v = X[(size_t)r * 128 + c];
        s += v;
        sq += v * v;
    }
    sh[t] = s;
    __syncthreads();
    if (half == 0) psum[(size_t)c * CSB + blockIdx.x] = s + sh[t + 128];
    __syncthreads();
    sh[t] = sq;
    __syncthreads();
    if (half == 0) psq[(size_t)c * CSB + blockIdx.x] = sq + sh[t + 128];
}

__global__ __launch_bounds__(256) void colstats2_k(const float* __restrict__ psum,
                                                   const float* __restrict__ psq,
                                                   float* __restrict__ colsum,
                                                   float* __restrict__ colsq) {
    __shared__ float sh[256];
    int c = blockIdx.x;
    int t = threadIdx.x;
    float s = 0.f, sq = 0.f;
#pragma unroll
    for (int i = 0; i < CSB / 256; i++) {
        s += psum[(size_t)c * CSB + i * 256 + t];
        sq += psq[(size_t)c * CSB + i * 256 + t];
    }
    sh[t] = s;
    __syncthreads();
    for (int off = 128; off > 0; off >>= 1) {
        if (t < off) sh[t] += sh[t + off];
        __syncthreads();
    }
    if (t == 0) colsum[c] = sh[0];
    __syncthreads();
    sh[t] = sq;
    __syncthreads();
    for (int off = 128; off > 0; off >>= 1) {
        if (t < off) sh[t] += sh[t + off];
        __syncthreads();
    }
    if (t == 0) colsq[c] = sh[0];
}

__global__ void bn_prep_k(const float* __restrict__ colsum, const float* __restrict__ colsq,
                          const float* __restrict__ gamma, const float* __restrict__ beta,
                          const float* __restrict__ W2, float* __restrict__ W2p,
                          float* __restrict__ v2, float n) {
    __shared__ float s_s[128], s_t[128];
    int c = threadIdx.x;
    float mu = colsum[c] / n;
    float var = colsq[c] / n - mu * mu;
    float s = gamma[c] * rsqrtf(var + 1e-5f);
    float t = beta[c] - mu * s;
    s_s[c] = s;
    s_t[c] = t;
    __syncthreads();
    float acc = 0.f;
    for (int k = 0; k < 128; k++) {
        float w = W2[k * 128 + c];
        W2p[k * 128 + c] = s_s[k] * w;
        acc += s_t[k] * w;
    }
    v2[c] = acc;
}

extern "C" void kernel_launch(void* const* d_in, const int* in_sizes, int n_in,
                              void* d_out, int out_size, void* d_ws, size_t ws_size,
                              hipStream_t stream) {
    const float* feat = (const float*)d_in[0];
    const int* src = (const int*)d_in[1];
    const int* dst = (const int*)d_in[2];
    const float* W1 = (const float*)d_in[3];
    const float* b1 = (const float*)d_in[4];
    const float* gamma1 = (const float*)d_in[5];
    const float* beta1 = (const float*)d_in[6];
    const float* W2 = (const float*)d_in[7];
    const float* b2 = (const float*)d_in[8];
    const float* W3 = (const float*)d_in[9];
    const float* b3 = (const float*)d_in[10];
    float* out = (float*)d_out;

    int n = in_sizes[0] / NFEAT;
    int ne = in_sizes[1];
    int npass = (n + HCHUNK - 1) / HCHUNK;

    char* ws = (char*)d_ws;
    size_t off = 0;
    auto carve = [&](size_t bytes) -> void* {
        void* p = ws + off;
        off += (bytes + 255) & ~(size_t)255;
        return p;
    };
    float* h    = (float*)carve((size_t)n * NFEAT * 4);
    float* x    = (float*)carve((size_t)n * NFEAT * 4);
    int* esrc   = (int*)carve((size_t)ne * 4);
    int* din_   = (int*)carve((size_t)n * 4);
    float* ns   = (float*)carve((size_t)n * 4);
    float* ndv  = (float*)carve((size_t)n * 4);
    int* rp     = (int*)carve((size_t)(n + 1) * 4);
    int* parts  = (int*)carve(512 * 4);
    float* psum = (float*)carve((size_t)128 * CSB * 4);
    float* psq  = (float*)carve((size_t)128 * CSB * 4);
    float* colsum = (float*)carve(128 * 4);
    float* colsq  = (float*)carve(128 * 4);
    float* W2p  = (float*)carve(128 * 128 * 4);
    float* v2   = (float*)carve(128 * 4);

    // histogram partials alias h: each npass*HBLOCKS*HCHUNK/4 u32 = 16.8 MB; both
    // fit in h (51.2 MB); h first written by gemm1 (after CSR build).
    size_t hpart_elems = (size_t)npass * HBLOCKS * (HCHUNK / 4);
    unsigned int* hpartA = (unsigned int*)h;
    unsigned int* hpartB = hpartA + hpart_elems;

    int nbl = (n + 255) / 256;
    int sbl = (npass * (HCHUNK / 4) + 255) / 256;

    hist3_k<<<dim3(HBLOCKS, npass, 2), 256, 0, stream>>>(src, dst, ne, n, hpartA, hpartB);
    sum_prefix2_k<<<dim3(sbl, 2), 256, 0, stream>>>(hpartA, hpartB, din_, ns, ndv, n, npass);

    scan1_k<<<nbl, 256, 0, stream>>>(din_, rp, parts, n);
    scan2_k<<<1, 512, 0, stream>>>(parts, nbl);
    scan3_k<<<nbl, 256, 0, stream>>>(rp, parts, din_, n);
    fill2_k<<<dim3(HBLOCKS, npass), 256, 0, stream>>>(src, dst, rp, hpartB, esrc, ne, n);

    int agrid = (n + 3) / 4;

    // layer 1: relu(conv(features, W1, b1))
    gemm2_k<128, false><<<(n + 63) / 64, 256, 0, stream>>>(feat, W1, ns, nullptr, h, n);
    agg3_k<128, true><<<agrid, 256, 0, stream>>>(h, rp, esrc, ndv, b1, x, n);

    // batchnorm folded into W2
    colstats1_k<<<CSB, 256, 0, stream>>>(x, psum, psq, n);
    colstats2_k<<<128, 256, 0, stream>>>(psum, psq, colsum, colsq);
    bn_prep_k<<<1, 128, 0, stream>>>(colsum, colsq, gamma1, beta1, W2, W2p, v2, (float)n);

    // layer 2: relu(conv(BN(x), W2, b2))
    gemm2_k<128, true><<<(n + 63) / 64, 256, 0, stream>>>(x, W2p, ns, v2, h, n);
    agg3_k<128, true><<<agrid, 256, 0, stream>>>(h, rp, esrc, ndv, b2, x, n);

    // layer 3: conv(x, W3, b3) -> out
    gemm2_k<64, false><<<(n + 127) / 128, 256, 0, stream>>>(x, W3, ns, nullptr, h, n);
    agg3_k<64, false><<<agrid, 256, 0, stream>>>(h, rp, esrc, ndv, b3, out, n);
}